// Round 1
// 756.056 us; speedup vs baseline: 1.0774x; 1.0774x over previous
//
#include <hip/hip_runtime.h>
#include <cstdint>

// out = sign(x) @ (sign(fp - rowmean)*alpha)^T + bias ; exact i8 binary GEMM via MFMA
#define B_SZ   16384
#define IN_SZ  4096
#define OUT_SZ 4096

typedef int int4v  __attribute__((ext_vector_type(4)));
typedef int int16v __attribute__((ext_vector_type(16)));

__device__ __forceinline__ int sgn8(float v) { return (v > 0.f) - (v < 0.f); }

// ---------------- weight prep: one block (256 thr) per output row ----------------
__global__ __launch_bounds__(256) void wprep_kernel(const float* __restrict__ fp,
                                                    int8_t* __restrict__ wb,
                                                    float* __restrict__ alpha) {
    __shared__ float red[4];
    const int o = blockIdx.x;
    const int t = threadIdx.x;
    const float4* row = (const float4*)(fp + (size_t)o * IN_SZ);

    float4 v[4];
    float s = 0.f;
#pragma unroll
    for (int i = 0; i < 4; ++i) {
        v[i] = row[t + i * 256];
        s += (v[i].x + v[i].y) + (v[i].z + v[i].w);
    }
#pragma unroll
    for (int off = 32; off > 0; off >>= 1) s += __shfl_down(s, off, 64);
    if ((t & 63) == 0) red[t >> 6] = s;
    __syncthreads();
    const float mean = (red[0] + red[1] + red[2] + red[3]) * (1.f / IN_SZ);
    __syncthreads();

    int* wrow = (int*)(wb + (size_t)o * IN_SZ);
    float a = 0.f;
#pragma unroll
    for (int i = 0; i < 4; ++i) {
        const float dx = v[i].x - mean, dy = v[i].y - mean;
        const float dz = v[i].z - mean, dw = v[i].w - mean;
        a += fminf(fabsf(dx), 1.f) + fminf(fabsf(dy), 1.f)
           + fminf(fabsf(dz), 1.f) + fminf(fabsf(dw), 1.f);
        const int p = (sgn8(dx) & 0xff) | ((sgn8(dy) & 0xff) << 8)
                    | ((sgn8(dz) & 0xff) << 16) | (sgn8(dw) << 24);
        wrow[t + i * 256] = p;
    }
#pragma unroll
    for (int off = 32; off > 0; off >>= 1) a += __shfl_down(a, off, 64);
    if ((t & 63) == 0) red[t >> 6] = a;
    __syncthreads();
    if (t == 0) alpha[o] = (red[0] + red[1] + red[2] + red[3]) * (1.f / IN_SZ);
}

// ---------------- activation prep: sign(x) -> int8, 2 float4 per thread ----------------
__global__ __launch_bounds__(256) void xprep_kernel(const float* __restrict__ x,
                                                    int8_t* __restrict__ xb) {
    const size_t i = ((size_t)blockIdx.x * 256 + threadIdx.x) * 2;
    const float4 v0 = ((const float4*)x)[i];
    const float4 v1 = ((const float4*)x)[i + 1];
    int2 p;
    p.x = (sgn8(v0.x) & 0xff) | ((sgn8(v0.y) & 0xff) << 8)
        | ((sgn8(v0.z) & 0xff) << 16) | (sgn8(v0.w) << 24);
    p.y = (sgn8(v1.x) & 0xff) | ((sgn8(v1.y) & 0xff) << 8)
        | ((sgn8(v1.z) & 0xff) << 16) | (sgn8(v1.w) << 24);
    ((int2*)xb)[i / 2] = p;
}

// ---------------- i8 binary GEMM, 32x32x32 MFMA ----------------
// Block tile 256x128, BK=64, 4 waves in 2x2 of 128x64 wave tiles, acc[4][2].
// LDS: double-buffered, row-linear 64B rows (global_load_lds wave-uniform-base),
// XOR chunk swizzle (chunk ^= (row>>1)&3) applied BOTH on the per-lane global
// source address (write side) and on the ds_read address (read side) -> the
// ds_read_b128 fragment reads hit 8 distinct 16B bank-groups per 8-lane group
// (was ~16-way conflict: SQ_LDS_BANK_CONFLICT ~1e8 = 41% of kernel cycles).
// 2-phase prefetch: stage tile t+1 while computing tile t, 1 barrier/iter.
__global__ __launch_bounds__(256, 3) void gemm_kernel(const int8_t* __restrict__ Xb,
                                                      const int8_t* __restrict__ Wb,
                                                      const float* __restrict__ alpha,
                                                      const float* __restrict__ bias,
                                                      float* __restrict__ out) {
    __shared__ __align__(16) int8_t As[2][256 * 64];   // 2 x 16 KB
    __shared__ __align__(16) int8_t Bs[2][128 * 64];   // 2 x  8 KB

    const int tid  = threadIdx.x;
    const int lane = tid & 63;
    const int wave = tid >> 6;

    // XCD-bijective remap (2048 blocks, 8 XCDs -> 256-block contiguous chunks),
    // then GROUP_M=4 banding: each XCD works a 4-tall tm band across all tn
    // (A band = 4 x 1MB fits its 4MB L2; B tile shared by 4 consecutive blocks).
    const int bid     = blockIdx.x;                    // 0..2047
    const int logical = (bid & 7) * 256 + (bid >> 3);
    const int group   = logical >> 7;                  // 16 groups of (4 tm x 32 tn)
    const int rem     = logical & 127;
    const int tm = group * 4 + (rem & 3);              // 0..63  (256-row tiles)
    const int tn = rem >> 2;                           // 0..31  (128-col tiles)

    const int wm = (wave >> 1) * 128;
    const int wn = (wave & 1) * 64;

    // staging: wave stages 64 A-rows (4x16) and 32 B-rows (2x16); lane l writes
    // LDS slot l -> (row=l>>2, chunk=l&3); source chunk pre-XORed with f(row)=(row>>1)&3
    const int srow = lane >> 2;
    const int scol = ((lane & 3) ^ ((lane >> 3) & 3)) << 4;
    const int8_t* gA = Xb + (size_t)(tm * 256 + wave * 64 + srow) * IN_SZ + scol;
    const int8_t* gB = Wb + (size_t)(tn * 128 + wave * 32 + srow) * IN_SZ + scol;

    int16v acc[4][2] = {};               // 128 AGPRs

    const int frow  = lane & 31;         // fragment row (m / n)
    const int khalf = lane >> 5;         // which 16B of the 32B k-half
    const int fxor  = (lane >> 1) & 3;   // read-side chunk XOR = f(frow)

    auto stage = [&](int bb, int k0) {
#pragma unroll
        for (int j = 0; j < 4; ++j)
            __builtin_amdgcn_global_load_lds(
                (const __attribute__((address_space(1))) uint32_t*)(gA + k0 + (size_t)j * 16 * IN_SZ),
                (__attribute__((address_space(3))) uint32_t*)(&As[bb][(wave * 64 + j * 16) * 64]),
                16, 0, 0);
#pragma unroll
        for (int j = 0; j < 2; ++j)
            __builtin_amdgcn_global_load_lds(
                (const __attribute__((address_space(1))) uint32_t*)(gB + k0 + (size_t)j * 16 * IN_SZ),
                (__attribute__((address_space(3))) uint32_t*)(&Bs[bb][(wave * 32 + j * 16) * 64]),
                16, 0, 0);
    };

    stage(0, 0);
    __syncthreads();

    int bb = 0;
    for (int k0 = 0; k0 < IN_SZ; k0 += 64) {
        if (k0 + 64 < IN_SZ) stage(bb ^ 1, k0 + 64);   // prefetch next K-tile

#pragma unroll
        for (int s = 0; s < 2; ++s) {    // two 32-byte k-halves of the 64B row
            const int chunk = ((s * 2 + khalf) ^ fxor) << 4;
            int4v a[4], b[2];
#pragma unroll
            for (int i = 0; i < 4; ++i)
                a[i] = *(const int4v*)(&As[bb][(wm + i * 32 + frow) * 64 + chunk]);
#pragma unroll
            for (int j = 0; j < 2; ++j)
                b[j] = *(const int4v*)(&Bs[bb][(wn + j * 32 + frow) * 64 + chunk]);
#pragma unroll
            for (int i = 0; i < 4; ++i)
#pragma unroll
                for (int j = 0; j < 2; ++j)
                    acc[i][j] = __builtin_amdgcn_mfma_i32_32x32x32_i8(a[i], b[j], acc[i][j], 0, 0, 0);
        }
        __syncthreads();                 // drains prefetch (vmcnt) + read-before-overwrite
        bb ^= 1;
    }

    // epilogue: 32x32 C/D layout col=lane&31, row=(reg&3)+8*(reg>>2)+4*(lane>>5)
    // nontemporal stores: out (256MB) is write-once -> keep xb/wb LLC-resident.
    const int col = lane & 31;
    const int rbase = 4 * (lane >> 5);
#pragma unroll
    for (int j = 0; j < 2; ++j) {
        const int o = tn * 128 + wn + j * 32 + col;
        const float al = alpha[o];
        const float bi = bias[o];
#pragma unroll
        for (int i = 0; i < 4; ++i) {
            const size_t mbase = (size_t)(tm * 256 + wm + i * 32);
#pragma unroll
            for (int r = 0; r < 16; ++r) {
                const int row = (r & 3) + 8 * (r >> 2) + rbase;
                __builtin_nontemporal_store(al * (float)acc[i][j][r] + bi,
                                            &out[(mbase + row) * OUT_SZ + o]);
            }
        }
    }
}

extern "C" void kernel_launch(void* const* d_in, const int* in_sizes, int n_in,
                              void* d_out, int out_size, void* d_ws, size_t ws_size,
                              hipStream_t stream) {
    const float* x    = (const float*)d_in[0];   // [B, IN] fp32
    const float* fp   = (const float*)d_in[1];   // [OUT, IN] fp32
    const float* bias = (const float*)d_in[2];   // [OUT] fp32
    float* out = (float*)d_out;                  // [B, OUT] fp32

    int8_t* xb    = (int8_t*)d_ws;                       // 64 MiB
    int8_t* wb    = xb + (size_t)B_SZ * IN_SZ;           // 16 MiB
    float*  alpha = (float*)(wb + (size_t)OUT_SZ * IN_SZ);

    hipLaunchKernelGGL(wprep_kernel, dim3(OUT_SZ), dim3(256), 0, stream, fp, wb, alpha);
    hipLaunchKernelGGL(xprep_kernel, dim3(B_SZ * IN_SZ / 2048), dim3(256), 0, stream, x, xb);
    hipLaunchKernelGGL(gemm_kernel, dim3((B_SZ / 256) * (OUT_SZ / 128)), dim3(256), 0, stream,
                       xb, wb, alpha, bias, out);
}